// Round 42
// baseline (64.218 us; speedup 1.0000x reference)
//
#include <hip/hip_runtime.h>
#include <math.h>

#define BN_ 32768
#define SPP_ 64
#define HID_ 64

typedef float v2f __attribute__((ext_vector_type(2)));

__device__ __forceinline__ v2f pk_fma(v2f a, v2f b, v2f c) {
    v2f d;
    asm("v_pk_fma_f32 %0, %1, %2, %3" : "=v"(d) : "v"(a), "v"(b), "v"(c));
    return d;
}

__device__ __forceinline__ float softplus_f(float x) {
    return fmaxf(x, 0.f) + __logf(1.f + __expf(-fabsf(x)));
}

struct RayState {
    float f0, f1, f2, f3, f4, f5;   // MLP features
    float wgt, sw;                  // ndl/pdfs, spec_scalar*wgt
    float fr0, fr1, fr2;
    float wim;
};

__device__ __forceinline__ RayState shade_ray(
    const float* __restrict__ sp, const float* __restrict__ vd,
    const float* __restrict__ Kd, const float* __restrict__ Ks,
    const float* __restrict__ nrm, const float* __restrict__ rough,
    const float* __restrict__ smp, int ray, int lane)
{
    const float PI_F = 3.14159265358979323846f;
    RayState S;

    const float nx = nrm[ray * 3 + 0], ny = nrm[ray * 3 + 1], nz = nrm[ray * 3 + 2];
    const float vx = vd[ray * 3 + 0],  vy = vd[ray * 3 + 1],  vz = vd[ray * 3 + 2];
    const float kd0 = Kd[ray * 3 + 0], kd1 = Kd[ray * 3 + 1], kd2 = Kd[ray * 3 + 2];
    const float ks0 = Ks[ray * 3 + 0], ks1 = Ks[ray * 3 + 1], ks2 = Ks[ray * 3 + 2];
    const float rg  = rough[ray];
    const float spx = sp[ray * 3 + 0], spy = sp[ray * 3 + 1], spz = sp[ray * 3 + 2];

    const float sgn = (nz >= 0.f) ? 1.f : -1.f;
    const float a   = __fdividef(-1.f, sgn + nz);
    const float bb  = nx * ny * a;
    const float cx0 = 1.f + sgn * nx * nx * a, cx1 = sgn * bb,          cx2 = -sgn * nx;
    const float cy0 = bb,                      cy1 = sgn + ny * ny * a, cy2 = -ny;

    float wi0 = cx0 * vx + cx1 * vy + cx2 * vz;
    float wi1 = cy0 * vx + cy1 * vy + cy2 * vz;
    float wi2 = nx * vx + ny * vy + nz * vz;
    S.wim = (wi2 >= 1e-5f) ? 1.f : 0.f;
    wi2 = fmaxf(wi2, 1e-5f);
    {
        const float l2  = wi0 * wi0 + wi1 * wi1 + wi2 * wi2;
        const float inv = rsqrtf(fmaxf(l2, 1e-12f));
        wi0 *= inv; wi1 *= inv; wi2 *= inv;
    }

    const float alpha  = fmaxf(rg * rg, 1e-4f);
    const float alpha2 = alpha * alpha;
    const float dmean  = (kd0 + kd1 + kd2) * (1.f / 3.f);
    const float smean  = (ks0 + ks1 + ks2) * (1.f / 3.f);
    const float pS     = fmaxf(__fdividef(smean, dmean + smean + 1e-6f), 0.f);

    const long  sbase = ((long)ray * SPP_ + lane) * 3;
    const float s0 = smp[sbase + 0];
    const float u1 = smp[sbase + 1];
    const float u2 = smp[sbase + 2];

    const bool  sample_diffuse = (s0 >= pS);
    const float r   = __builtin_amdgcn_sqrtf(u1);
    // sin(2*pi*u2): v_sin/v_cos take revolutions, u2 in [0,1)
    const float sphi = __builtin_amdgcn_sinf(u2);
    const float cphi = __builtin_amdgcn_cosf(u2);

    const float ld0 = r * cphi, ld1 = r * sphi;
    const float ld2 = __builtin_amdgcn_sqrtf(fmaxf(1.f - u1, 0.f));

    float c2 = __fdividef(1.f - u1, 1.f + (alpha2 - 1.f) * u1);
    c2 = fminf(fmaxf(c2, 0.f), 1.f);
    const float ct = __builtin_amdgcn_sqrtf(c2);
    const float st = __builtin_amdgcn_sqrtf(1.f - c2);
    const float h0 = st * cphi, h1 = st * sphi, h2 = ct;

    const float dwh  = wi0 * h0 + wi1 * h1 + wi2 * h2;
    const float lsp0 = 2.f * dwh * h0 - wi0;
    const float lsp1 = 2.f * dwh * h1 - wi1;
    const float lsp2 = 2.f * dwh * h2 - wi2;

    const float wo0 = sample_diffuse ? ld0 : lsp0;
    const float wo1 = sample_diffuse ? ld1 : lsp1;
    const float wo2 = sample_diffuse ? ld2 : lsp2;

    const float pdf_diff = fmaxf(wo2, 0.f) * (1.f / PI_F);

    float hm0 = wi0 + wo0, hm1 = wi1 + wo1, hm2 = wi2 + wo2;
    {
        const float l2  = hm0 * hm0 + hm1 * hm1 + hm2 * hm2;
        const float inv = rsqrtf(fmaxf(l2, 1e-12f));
        hm0 *= inv; hm1 *= inv; hm2 *= inv;
    }
    const float hz = hm2;
    const float dd = hz * hz * (alpha2 - 1.f) + 1.f;
    const float D  = __fdividef(alpha2, PI_F * dd * dd);

    const float woh      = wo0 * hm0 + wo1 * hm1 + wo2 * hm2;
    const float pdf_spec = __fdividef(D * fmaxf(hz, 0.f), 4.f * fmaxf(woh, 1e-6f));
    float pdfs = pS * pdf_spec + (1.f - pS) * pdf_diff;
    pdfs = fmaxf(pdfs, 1e-5f);

    const bool  womask = (wo2 > 0.f);
    const float wiz = fmaxf(wi2, 1e-6f);
    const float woz = fmaxf(wo2, 1e-6f);
    const float G1i = __fdividef(2.f * wiz,
        wiz + __builtin_amdgcn_sqrtf(alpha2 + (1.f - alpha2) * wiz * wiz));
    const float G1o = __fdividef(2.f * woz,
        woz + __builtin_amdgcn_sqrtf(alpha2 + (1.f - alpha2) * woz * woz));
    const float G   = G1i * G1o;

    float wih = wi0 * hm0 + wi1 * hm1 + wi2 * hm2;
    wih = fminf(fmaxf(wih, 0.f), 1.f);
    const float t1m = 1.f - wih;
    const float t2s = t1m * t1m;
    const float f5  = t2s * t2s * t1m;
    S.fr0 = ks0 + (1.f - ks0) * f5;
    S.fr1 = ks1 + (1.f - ks1) * f5;
    S.fr2 = ks2 + (1.f - ks2) * f5;

    float ss = __fdividef(D * G, 4.f * wiz * woz);
    if (!womask) ss = 0.f;

    const float dx = wo0 * cx0 + wo1 * cy0 + wo2 * nx;
    const float dy = wo0 * cx1 + wo1 * cy1 + wo2 * ny;
    const float dz = wo0 * cx2 + wo1 * cy2 + wo2 * nz;

    S.f0 = spx + 0.01f * dx;
    S.f1 = spy + 0.01f * dy;
    S.f2 = spz + 0.01f * dz;
    S.f3 = dx; S.f4 = dy; S.f5 = dz;

    const float ndl = fmaxf(wo2, 0.f);
    S.wgt = __fdividef(ndl, pdfs);
    S.sw  = ss * S.wgt;
    return S;
}

// Pack pair-rows into workspace: row p = {W1 pairs (12), b1 pair (2),
// W2 pairs (6)} for hidden units 2p, 2p+1. 20 floats per row, 32 rows.
__global__ void pack_weights(const float* __restrict__ W1,
                             const float* __restrict__ b1,
                             const float* __restrict__ W2,
                             const float* __restrict__ b2,
                             float* __restrict__ wp)
{
    const int p = threadIdx.x;
    if (p < 32) {
        const int j0 = 2 * p, j1 = 2 * p + 1;
        float* row = wp + p * 20;
        #pragma unroll
        for (int k = 0; k < 6; ++k) {
            row[2 * k + 0] = W1[k * 64 + j0];
            row[2 * k + 1] = W1[k * 64 + j1];
        }
        row[12] = b1[j0];
        row[13] = b1[j1];
        #pragma unroll
        for (int c = 0; c < 3; ++c) {
            row[14 + 2 * c] = W2[j0 * 3 + c];
            row[15 + 2 * c] = W2[j1 * 3 + c];
        }
    }
    if (p < 4) wp[640 + p] = (p < 3) ? b2[p] : 0.f;
}

__global__ __launch_bounds__(256) void render_kernel(
    const float* __restrict__ sp, const float* __restrict__ vd,
    const float* __restrict__ Kd, const float* __restrict__ Ks,
    const float* __restrict__ nrm, const float* __restrict__ rough,
    const float* __restrict__ smp,
    const float* __restrict__ wp,   // packed weights in workspace
    float* __restrict__ out)
{
    const float PI_F = 3.14159265358979323846f;

    const int tid  = threadIdx.x;
    const int wave = tid >> 6;
    const int lane = tid & 63;
    const int rayA = (blockIdx.x << 3) + (wave << 1);
    const int rayB = rayA + 1;

    RayState A = shade_ray(sp, vd, Kd, Ks, nrm, rough, smp, rayA, lane);
    RayState B = shade_ray(sp, vd, Kd, Ks, nrm, rough, smp, rayB, lane);

    const v2f fA0 = {A.f0, A.f0}, fA1 = {A.f1, A.f1}, fA2 = {A.f2, A.f2};
    const v2f fA3 = {A.f3, A.f3}, fA4 = {A.f4, A.f4}, fA5 = {A.f5, A.f5};
    const v2f fB0 = {B.f0, B.f0}, fB1 = {B.f1, B.f1}, fB2 = {B.f2, B.f2};
    const v2f fB3 = {B.f3, B.f3}, fB4 = {B.f4, B.f4}, fB5 = {B.f5, B.f5};

    v2f accA0 = {0.f, 0.f}, accA1 = {0.f, 0.f}, accA2 = {0.f, 0.f};
    v2f accB0 = {0.f, 0.f}, accB1 = {0.f, 0.f}, accB2 = {0.f, 0.f};

    #pragma unroll 2
    for (int p = 0; p < 32; ++p) {
        // Wave-uniform reads -> scalar loads through K$ (no LDS, no VMEM).
        const float* row = wp + p * 20;
        const v2f w0 = {row[0],  row[1]},  w1 = {row[2],  row[3]};
        const v2f w2 = {row[4],  row[5]},  w3 = {row[6],  row[7]};
        const v2f w4 = {row[8],  row[9]},  w5 = {row[10], row[11]};
        const v2f b1p = {row[12], row[13]};
        const v2f u0 = {row[14], row[15]};
        const v2f u1 = {row[16], row[17]};
        const v2f u2 = {row[18], row[19]};

        v2f hA = pk_fma(fA0, w0, b1p);
        hA = pk_fma(fA1, w1, hA);
        hA = pk_fma(fA2, w2, hA);
        hA = pk_fma(fA3, w3, hA);
        hA = pk_fma(fA4, w4, hA);
        hA = pk_fma(fA5, w5, hA);
        hA.x = fmaxf(hA.x, 0.f);
        hA.y = fmaxf(hA.y, 0.f);

        v2f hB = pk_fma(fB0, w0, b1p);
        hB = pk_fma(fB1, w1, hB);
        hB = pk_fma(fB2, w2, hB);
        hB = pk_fma(fB3, w3, hB);
        hB = pk_fma(fB4, w4, hB);
        hB = pk_fma(fB5, w5, hB);
        hB.x = fmaxf(hB.x, 0.f);
        hB.y = fmaxf(hB.y, 0.f);

        accA0 = pk_fma(hA, u0, accA0);
        accA1 = pk_fma(hA, u1, accA1);
        accA2 = pk_fma(hA, u2, accA2);
        accB0 = pk_fma(hB, u0, accB0);
        accB1 = pk_fma(hB, u1, accB1);
        accB2 = pk_fma(hB, u2, accB2);
    }

    const float c0 = wp[640], c1 = wp[641], c2b = wp[642];
    float a0 = softplus_f(accA0.x + accA0.y + c0);
    float a1 = softplus_f(accA1.x + accA1.y + c1);
    float a2 = softplus_f(accA2.x + accA2.y + c2b);
    float b0 = softplus_f(accB0.x + accB0.y + c0);
    float b1v = softplus_f(accB1.x + accB1.y + c1);
    float b2v = softplus_f(accB2.x + accB2.y + c2b);

    float adA0 = A.wgt * a0, adA1 = A.wgt * a1, adA2 = A.wgt * a2;
    float asA0 = A.sw * A.fr0 * a0, asA1 = A.sw * A.fr1 * a1, asA2 = A.sw * A.fr2 * a2;
    float adB0 = B.wgt * b0, adB1 = B.wgt * b1v, adB2 = B.wgt * b2v;
    float asB0 = B.sw * B.fr0 * b0, asB1 = B.sw * B.fr1 * b1v, asB2 = B.sw * B.fr2 * b2v;

    #pragma unroll
    for (int off = 32; off > 0; off >>= 1) {
        adA0 += __shfl_down(adA0, off);
        adA1 += __shfl_down(adA1, off);
        adA2 += __shfl_down(adA2, off);
        asA0 += __shfl_down(asA0, off);
        asA1 += __shfl_down(asA1, off);
        asA2 += __shfl_down(asA2, off);
        adB0 += __shfl_down(adB0, off);
        adB1 += __shfl_down(adB1, off);
        adB2 += __shfl_down(adB2, off);
        asB0 += __shfl_down(asB0, off);
        asB1 += __shfl_down(asB1, off);
        asB2 += __shfl_down(asB2, off);
    }

    if (lane == 0) {
        const float cdi = 1.f / (PI_F * (float)SPP_);
        const float csi = 1.f / (float)SPP_;
        out[rayA * 3 + 0] = Kd[rayA * 3 + 0] * cdi * adA0;
        out[rayA * 3 + 1] = Kd[rayA * 3 + 1] * cdi * adA1;
        out[rayA * 3 + 2] = Kd[rayA * 3 + 2] * cdi * adA2;
        out[BN_ * 3 + rayA * 3 + 0] = asA0 * csi;
        out[BN_ * 3 + rayA * 3 + 1] = asA1 * csi;
        out[BN_ * 3 + rayA * 3 + 2] = asA2 * csi;
        out[BN_ * 6 + rayA] = A.wim;

        out[rayB * 3 + 0] = Kd[rayB * 3 + 0] * cdi * adB0;
        out[rayB * 3 + 1] = Kd[rayB * 3 + 1] * cdi * adB1;
        out[rayB * 3 + 2] = Kd[rayB * 3 + 2] * cdi * adB2;
        out[BN_ * 3 + rayB * 3 + 0] = asB0 * csi;
        out[BN_ * 3 + rayB * 3 + 1] = asB1 * csi;
        out[BN_ * 3 + rayB * 3 + 2] = asB2 * csi;
        out[BN_ * 6 + rayB] = B.wim;
    }
}

extern "C" void kernel_launch(void* const* d_in, const int* in_sizes, int n_in,
                              void* d_out, int out_size, void* d_ws, size_t ws_size,
                              hipStream_t stream) {
    const float* sp    = (const float*)d_in[0];
    const float* vd    = (const float*)d_in[1];
    const float* Kd    = (const float*)d_in[2];
    const float* Ks    = (const float*)d_in[3];
    const float* nrm   = (const float*)d_in[4];
    const float* rough = (const float*)d_in[5];
    const float* smp   = (const float*)d_in[6];
    const float* W1    = (const float*)d_in[7];
    const float* b1    = (const float*)d_in[8];
    const float* W2    = (const float*)d_in[9];
    const float* b2    = (const float*)d_in[10];
    float* out = (float*)d_out;
    float* wp  = (float*)d_ws;   // 644 floats used

    pack_weights<<<1, 64, 0, stream>>>(W1, b1, W2, b2, wp);

    dim3 grid(BN_ / 8);
    dim3 block(256);
    render_kernel<<<grid, block, 0, stream>>>(sp, vd, Kd, Ks, nrm, rough, smp,
                                              wp, out);
}

// Round 43
// 57.276 us; speedup vs baseline: 1.1212x; 1.1212x over previous
//
#include <hip/hip_runtime.h>
#include <math.h>

#define BN_ 32768
#define SPP_ 64
#define HID_ 64

typedef float v2f __attribute__((ext_vector_type(2)));

__device__ __forceinline__ v2f pk_fma(v2f a, v2f b, v2f c) {
    v2f d;
    asm("v_pk_fma_f32 %0, %1, %2, %3" : "=v"(d) : "v"(a), "v"(b), "v"(c));
    return d;
}

__device__ __forceinline__ float softplus_f(float x) {
    return fmaxf(x, 0.f) + __logf(1.f + __expf(-fabsf(x)));
}

struct RayState {
    float f0, f1, f2, f3, f4, f5;   // MLP features
    float wgt, sw;                  // ndl/pdfs, spec_scalar*wgt
    float fr0, fr1, fr2;
    float wim;
};

__device__ __forceinline__ RayState shade_ray(
    const float* __restrict__ sp, const float* __restrict__ vd,
    const float* __restrict__ Kd, const float* __restrict__ Ks,
    const float* __restrict__ nrm, const float* __restrict__ rough,
    const float* __restrict__ smp, int ray, int lane)
{
    const float PI_F = 3.14159265358979323846f;
    RayState S;

    const float nx = nrm[ray * 3 + 0], ny = nrm[ray * 3 + 1], nz = nrm[ray * 3 + 2];
    const float vx = vd[ray * 3 + 0],  vy = vd[ray * 3 + 1],  vz = vd[ray * 3 + 2];
    const float kd0 = Kd[ray * 3 + 0], kd1 = Kd[ray * 3 + 1], kd2 = Kd[ray * 3 + 2];
    const float ks0 = Ks[ray * 3 + 0], ks1 = Ks[ray * 3 + 1], ks2 = Ks[ray * 3 + 2];
    const float rg  = rough[ray];
    const float spx = sp[ray * 3 + 0], spy = sp[ray * 3 + 1], spz = sp[ray * 3 + 2];

    const float sgn = (nz >= 0.f) ? 1.f : -1.f;
    const float a   = __fdividef(-1.f, sgn + nz);
    const float bb  = nx * ny * a;
    const float cx0 = 1.f + sgn * nx * nx * a, cx1 = sgn * bb,          cx2 = -sgn * nx;
    const float cy0 = bb,                      cy1 = sgn + ny * ny * a, cy2 = -ny;

    float wi0 = cx0 * vx + cx1 * vy + cx2 * vz;
    float wi1 = cy0 * vx + cy1 * vy + cy2 * vz;
    float wi2 = nx * vx + ny * vy + nz * vz;
    S.wim = (wi2 >= 1e-5f) ? 1.f : 0.f;
    wi2 = fmaxf(wi2, 1e-5f);
    {
        const float l2  = wi0 * wi0 + wi1 * wi1 + wi2 * wi2;
        const float inv = rsqrtf(fmaxf(l2, 1e-12f));
        wi0 *= inv; wi1 *= inv; wi2 *= inv;
    }

    const float alpha  = fmaxf(rg * rg, 1e-4f);
    const float alpha2 = alpha * alpha;
    const float dmean  = (kd0 + kd1 + kd2) * (1.f / 3.f);
    const float smean  = (ks0 + ks1 + ks2) * (1.f / 3.f);
    const float pS     = fmaxf(__fdividef(smean, dmean + smean + 1e-6f), 0.f);

    const long  sbase = ((long)ray * SPP_ + lane) * 3;
    const float s0 = smp[sbase + 0];
    const float u1 = smp[sbase + 1];
    const float u2 = smp[sbase + 2];

    const bool  sample_diffuse = (s0 >= pS);
    const float r   = __builtin_amdgcn_sqrtf(u1);
    // sin(2*pi*u2): v_sin/v_cos take revolutions, u2 in [0,1)
    const float sphi = __builtin_amdgcn_sinf(u2);
    const float cphi = __builtin_amdgcn_cosf(u2);

    const float ld0 = r * cphi, ld1 = r * sphi;
    const float ld2 = __builtin_amdgcn_sqrtf(fmaxf(1.f - u1, 0.f));

    float c2 = __fdividef(1.f - u1, 1.f + (alpha2 - 1.f) * u1);
    c2 = fminf(fmaxf(c2, 0.f), 1.f);
    const float ct = __builtin_amdgcn_sqrtf(c2);
    const float st = __builtin_amdgcn_sqrtf(1.f - c2);
    const float h0 = st * cphi, h1 = st * sphi, h2 = ct;

    const float dwh  = wi0 * h0 + wi1 * h1 + wi2 * h2;
    const float lsp0 = 2.f * dwh * h0 - wi0;
    const float lsp1 = 2.f * dwh * h1 - wi1;
    const float lsp2 = 2.f * dwh * h2 - wi2;

    const float wo0 = sample_diffuse ? ld0 : lsp0;
    const float wo1 = sample_diffuse ? ld1 : lsp1;
    const float wo2 = sample_diffuse ? ld2 : lsp2;

    const float pdf_diff = fmaxf(wo2, 0.f) * (1.f / PI_F);

    float hm0 = wi0 + wo0, hm1 = wi1 + wo1, hm2 = wi2 + wo2;
    {
        const float l2  = hm0 * hm0 + hm1 * hm1 + hm2 * hm2;
        const float inv = rsqrtf(fmaxf(l2, 1e-12f));
        hm0 *= inv; hm1 *= inv; hm2 *= inv;
    }
    const float hz = hm2;
    const float dd = hz * hz * (alpha2 - 1.f) + 1.f;
    const float D  = __fdividef(alpha2, PI_F * dd * dd);

    const float woh      = wo0 * hm0 + wo1 * hm1 + wo2 * hm2;
    const float pdf_spec = __fdividef(D * fmaxf(hz, 0.f), 4.f * fmaxf(woh, 1e-6f));
    float pdfs = pS * pdf_spec + (1.f - pS) * pdf_diff;
    pdfs = fmaxf(pdfs, 1e-5f);

    const bool  womask = (wo2 > 0.f);
    const float wiz = fmaxf(wi2, 1e-6f);
    const float woz = fmaxf(wo2, 1e-6f);
    const float G1i = __fdividef(2.f * wiz,
        wiz + __builtin_amdgcn_sqrtf(alpha2 + (1.f - alpha2) * wiz * wiz));
    const float G1o = __fdividef(2.f * woz,
        woz + __builtin_amdgcn_sqrtf(alpha2 + (1.f - alpha2) * woz * woz));
    const float G   = G1i * G1o;

    float wih = wi0 * hm0 + wi1 * hm1 + wi2 * hm2;
    wih = fminf(fmaxf(wih, 0.f), 1.f);
    const float t1m = 1.f - wih;
    const float t2s = t1m * t1m;
    const float f5  = t2s * t2s * t1m;
    S.fr0 = ks0 + (1.f - ks0) * f5;
    S.fr1 = ks1 + (1.f - ks1) * f5;
    S.fr2 = ks2 + (1.f - ks2) * f5;

    float ss = __fdividef(D * G, 4.f * wiz * woz);
    if (!womask) ss = 0.f;

    const float dx = wo0 * cx0 + wo1 * cy0 + wo2 * nx;
    const float dy = wo0 * cx1 + wo1 * cy1 + wo2 * ny;
    const float dz = wo0 * cx2 + wo1 * cy2 + wo2 * nz;

    S.f0 = spx + 0.01f * dx;
    S.f1 = spy + 0.01f * dy;
    S.f2 = spz + 0.01f * dz;
    S.f3 = dx; S.f4 = dy; S.f5 = dz;

    const float ndl = fmaxf(wo2, 0.f);
    S.wgt = __fdividef(ndl, pdfs);
    S.sw  = ss * S.wgt;
    return S;
}

__global__ __launch_bounds__(256) void render_kernel(
    const float* __restrict__ sp, const float* __restrict__ vd,
    const float* __restrict__ Kd, const float* __restrict__ Ks,
    const float* __restrict__ nrm, const float* __restrict__ rough,
    const float* __restrict__ smp,
    const float* __restrict__ W1, const float* __restrict__ b1,
    const float* __restrict__ W2, const float* __restrict__ b2,
    float* __restrict__ out)
{
    const float PI_F = 3.14159265358979323846f;

    // Pair-packed weights: row p (p=0..31) covers hidden units 2p, 2p+1.
    __shared__ __align__(16) float sPk[32][20];
    __shared__ float sb2[4];

    const int tid = threadIdx.x;
    if (tid < 32) {
        const int p = tid, j0 = 2 * tid, j1 = 2 * tid + 1;
        #pragma unroll
        for (int k = 0; k < 6; ++k) {
            sPk[p][2 * k + 0] = W1[k * 64 + j0];
            sPk[p][2 * k + 1] = W1[k * 64 + j1];
        }
        sPk[p][12] = b1[j0];
        sPk[p][13] = b1[j1];
        #pragma unroll
        for (int c = 0; c < 3; ++c) {
            sPk[p][14 + 2 * c] = W2[j0 * 3 + c];
            sPk[p][15 + 2 * c] = W2[j1 * 3 + c];
        }
    }
    if (tid < 3) sb2[tid] = b2[tid];
    __syncthreads();

    const int wave = tid >> 6;
    const int lane = tid & 63;
    const int rayA = (blockIdx.x << 3) + (wave << 1);
    const int rayB = rayA + 1;

    RayState A = shade_ray(sp, vd, Kd, Ks, nrm, rough, smp, rayA, lane);
    RayState B = shade_ray(sp, vd, Kd, Ks, nrm, rough, smp, rayB, lane);

    const v2f fA0 = {A.f0, A.f0}, fA1 = {A.f1, A.f1}, fA2 = {A.f2, A.f2};
    const v2f fA3 = {A.f3, A.f3}, fA4 = {A.f4, A.f4}, fA5 = {A.f5, A.f5};
    const v2f fB0 = {B.f0, B.f0}, fB1 = {B.f1, B.f1}, fB2 = {B.f2, B.f2};
    const v2f fB3 = {B.f3, B.f3}, fB4 = {B.f4, B.f4}, fB5 = {B.f5, B.f5};

    v2f accA0 = {0.f, 0.f}, accA1 = {0.f, 0.f}, accA2 = {0.f, 0.f};
    v2f accB0 = {0.f, 0.f}, accB1 = {0.f, 0.f}, accB2 = {0.f, 0.f};

    #pragma unroll 4
    for (int p = 0; p < 32; ++p) {
        const float4 q0 = *(const float4*)&sPk[p][0];
        const float4 q1 = *(const float4*)&sPk[p][4];
        const float4 q2 = *(const float4*)&sPk[p][8];
        const float4 q3 = *(const float4*)&sPk[p][12];
        const float4 q4 = *(const float4*)&sPk[p][16];
        const v2f w0 = {q0.x, q0.y}, w1 = {q0.z, q0.w};
        const v2f w2 = {q1.x, q1.y}, w3 = {q1.z, q1.w};
        const v2f w4 = {q2.x, q2.y}, w5 = {q2.z, q2.w};
        const v2f b1p = {q3.x, q3.y};
        const v2f u0 = {q3.z, q3.w}, u1 = {q4.x, q4.y}, u2 = {q4.z, q4.w};

        v2f hA = pk_fma(fA0, w0, b1p);
        hA = pk_fma(fA1, w1, hA);
        hA = pk_fma(fA2, w2, hA);
        hA = pk_fma(fA3, w3, hA);
        hA = pk_fma(fA4, w4, hA);
        hA = pk_fma(fA5, w5, hA);
        hA.x = fmaxf(hA.x, 0.f);
        hA.y = fmaxf(hA.y, 0.f);

        v2f hB = pk_fma(fB0, w0, b1p);
        hB = pk_fma(fB1, w1, hB);
        hB = pk_fma(fB2, w2, hB);
        hB = pk_fma(fB3, w3, hB);
        hB = pk_fma(fB4, w4, hB);
        hB = pk_fma(fB5, w5, hB);
        hB.x = fmaxf(hB.x, 0.f);
        hB.y = fmaxf(hB.y, 0.f);

        accA0 = pk_fma(hA, u0, accA0);
        accA1 = pk_fma(hA, u1, accA1);
        accA2 = pk_fma(hA, u2, accA2);
        accB0 = pk_fma(hB, u0, accB0);
        accB1 = pk_fma(hB, u1, accB1);
        accB2 = pk_fma(hB, u2, accB2);
    }

    float a0 = softplus_f(accA0.x + accA0.y + sb2[0]);
    float a1 = softplus_f(accA1.x + accA1.y + sb2[1]);
    float a2 = softplus_f(accA2.x + accA2.y + sb2[2]);
    float b0 = softplus_f(accB0.x + accB0.y + sb2[0]);
    float b1v = softplus_f(accB1.x + accB1.y + sb2[1]);
    float b2v = softplus_f(accB2.x + accB2.y + sb2[2]);

    float adA0 = A.wgt * a0, adA1 = A.wgt * a1, adA2 = A.wgt * a2;
    float asA0 = A.sw * A.fr0 * a0, asA1 = A.sw * A.fr1 * a1, asA2 = A.sw * A.fr2 * a2;
    float adB0 = B.wgt * b0, adB1 = B.wgt * b1v, adB2 = B.wgt * b2v;
    float asB0 = B.sw * B.fr0 * b0, asB1 = B.sw * B.fr1 * b1v, asB2 = B.sw * B.fr2 * b2v;

    #pragma unroll
    for (int off = 32; off > 0; off >>= 1) {
        adA0 += __shfl_down(adA0, off);
        adA1 += __shfl_down(adA1, off);
        adA2 += __shfl_down(adA2, off);
        asA0 += __shfl_down(asA0, off);
        asA1 += __shfl_down(asA1, off);
        asA2 += __shfl_down(asA2, off);
        adB0 += __shfl_down(adB0, off);
        adB1 += __shfl_down(adB1, off);
        adB2 += __shfl_down(adB2, off);
        asB0 += __shfl_down(asB0, off);
        asB1 += __shfl_down(asB1, off);
        asB2 += __shfl_down(asB2, off);
    }

    if (lane == 0) {
        const float cdi = 1.f / (PI_F * (float)SPP_);
        const float csi = 1.f / (float)SPP_;
        out[rayA * 3 + 0] = Kd[rayA * 3 + 0] * cdi * adA0;
        out[rayA * 3 + 1] = Kd[rayA * 3 + 1] * cdi * adA1;
        out[rayA * 3 + 2] = Kd[rayA * 3 + 2] * cdi * adA2;
        out[BN_ * 3 + rayA * 3 + 0] = asA0 * csi;
        out[BN_ * 3 + rayA * 3 + 1] = asA1 * csi;
        out[BN_ * 3 + rayA * 3 + 2] = asA2 * csi;
        out[BN_ * 6 + rayA] = A.wim;

        out[rayB * 3 + 0] = Kd[rayB * 3 + 0] * cdi * adB0;
        out[rayB * 3 + 1] = Kd[rayB * 3 + 1] * cdi * adB1;
        out[rayB * 3 + 2] = Kd[rayB * 3 + 2] * cdi * adB2;
        out[BN_ * 3 + rayB * 3 + 0] = asB0 * csi;
        out[BN_ * 3 + rayB * 3 + 1] = asB1 * csi;
        out[BN_ * 3 + rayB * 3 + 2] = asB2 * csi;
        out[BN_ * 6 + rayB] = B.wim;
    }
}

extern "C" void kernel_launch(void* const* d_in, const int* in_sizes, int n_in,
                              void* d_out, int out_size, void* d_ws, size_t ws_size,
                              hipStream_t stream) {
    const float* sp    = (const float*)d_in[0];
    const float* vd    = (const float*)d_in[1];
    const float* Kd    = (const float*)d_in[2];
    const float* Ks    = (const float*)d_in[3];
    const float* nrm   = (const float*)d_in[4];
    const float* rough = (const float*)d_in[5];
    const float* smp   = (const float*)d_in[6];
    const float* W1    = (const float*)d_in[7];
    const float* b1    = (const float*)d_in[8];
    const float* W2    = (const float*)d_in[9];
    const float* b2    = (const float*)d_in[10];
    float* out = (float*)d_out;

    dim3 grid(BN_ / 8);
    dim3 block(256);
    render_kernel<<<grid, block, 0, stream>>>(sp, vd, Kd, Ks, nrm, rough, smp,
                                              W1, b1, W2, b2, out);
}

// Round 45
// 55.098 us; speedup vs baseline: 1.1655x; 1.0395x over previous
//
#include <hip/hip_runtime.h>
#include <math.h>

#define BN_ 32768
#define SPP_ 64
#define HID_ 64

typedef float v2f __attribute__((ext_vector_type(2)));

__device__ __forceinline__ v2f pk_fma(v2f a, v2f b, v2f c) {
    v2f d;
    asm("v_pk_fma_f32 %0, %1, %2, %3" : "=v"(d) : "v"(a), "v"(b), "v"(c));
    return d;
}
__device__ __forceinline__ v2f pk2(float a, float b) { v2f r; r.x = a; r.y = b; return r; }
__device__ __forceinline__ v2f pk_bcast(float a) { return pk2(a, a); }
__device__ __forceinline__ v2f pk_sqrt(v2f a) {
    return pk2(__builtin_amdgcn_sqrtf(a.x), __builtin_amdgcn_sqrtf(a.y));
}
__device__ __forceinline__ v2f pk_div(v2f a, v2f b) {
    return pk2(__fdividef(a.x, b.x), __fdividef(a.y, b.y));
}
__device__ __forceinline__ v2f pk_maxs(v2f a, float s) {
    return pk2(fmaxf(a.x, s), fmaxf(a.y, s));
}
__device__ __forceinline__ v2f pk_rsq_clamp(v2f a) {
    return pk2(rsqrtf(fmaxf(a.x, 1e-12f)), rsqrtf(fmaxf(a.y, 1e-12f)));
}

__device__ __forceinline__ float softplus_f(float x) {
    return fmaxf(x, 0.f) + __logf(1.f + __expf(-fabsf(x)));
}

struct PairState {
    v2f f0, f1, f2, f3, f4, f5;     // MLP features {rayA, rayB}
    v2f wgt, sw, fr0, fr1, fr2;
    float wimA, wimB;
};

__device__ __forceinline__ PairState shade_pair(
    const float* __restrict__ sp, const float* __restrict__ vd,
    const float* __restrict__ Kd, const float* __restrict__ Ks,
    const float* __restrict__ nrm, const float* __restrict__ rough,
    const float* __restrict__ smp, int rayA, int rayB, int lane)
{
    const float PI_F = 3.14159265358979323846f;
    PairState S;

    const v2f nx = pk2(nrm[rayA * 3 + 0], nrm[rayB * 3 + 0]);
    const v2f ny = pk2(nrm[rayA * 3 + 1], nrm[rayB * 3 + 1]);
    const v2f nz = pk2(nrm[rayA * 3 + 2], nrm[rayB * 3 + 2]);
    const v2f vx = pk2(vd[rayA * 3 + 0], vd[rayB * 3 + 0]);
    const v2f vy = pk2(vd[rayA * 3 + 1], vd[rayB * 3 + 1]);
    const v2f vz = pk2(vd[rayA * 3 + 2], vd[rayB * 3 + 2]);
    const v2f kd0 = pk2(Kd[rayA * 3 + 0], Kd[rayB * 3 + 0]);
    const v2f kd1 = pk2(Kd[rayA * 3 + 1], Kd[rayB * 3 + 1]);
    const v2f kd2 = pk2(Kd[rayA * 3 + 2], Kd[rayB * 3 + 2]);
    const v2f ks0 = pk2(Ks[rayA * 3 + 0], Ks[rayB * 3 + 0]);
    const v2f ks1 = pk2(Ks[rayA * 3 + 1], Ks[rayB * 3 + 1]);
    const v2f ks2 = pk2(Ks[rayA * 3 + 2], Ks[rayB * 3 + 2]);
    const v2f rg  = pk2(rough[rayA], rough[rayB]);
    const v2f spx = pk2(sp[rayA * 3 + 0], sp[rayB * 3 + 0]);
    const v2f spy = pk2(sp[rayA * 3 + 1], sp[rayB * 3 + 1]);
    const v2f spz = pk2(sp[rayA * 3 + 2], sp[rayB * 3 + 2]);

    const v2f one = pk_bcast(1.f);

    v2f sgn;
    sgn.x = (nz.x >= 0.f) ? 1.f : -1.f;
    sgn.y = (nz.y >= 0.f) ? 1.f : -1.f;
    const v2f a   = pk_div(pk_bcast(-1.f), sgn + nz);
    const v2f bb  = nx * ny * a;
    const v2f cx0 = one + sgn * nx * nx * a;
    const v2f cx1 = sgn * bb;
    const v2f cx2 = -(sgn * nx);
    const v2f cy0 = bb;
    const v2f cy1 = sgn + ny * ny * a;
    const v2f cy2 = -ny;

    v2f wi0 = cx0 * vx + cx1 * vy + cx2 * vz;
    v2f wi1 = cy0 * vx + cy1 * vy + cy2 * vz;
    v2f wi2 = nx * vx + ny * vy + nz * vz;
    S.wimA = (wi2.x >= 1e-5f) ? 1.f : 0.f;
    S.wimB = (wi2.y >= 1e-5f) ? 1.f : 0.f;
    wi2 = pk_maxs(wi2, 1e-5f);
    {
        const v2f l2  = wi0 * wi0 + wi1 * wi1 + wi2 * wi2;
        const v2f inv = pk_rsq_clamp(l2);
        wi0 *= inv; wi1 *= inv; wi2 *= inv;
    }

    const v2f alpha  = pk_maxs(rg * rg, 1e-4f);
    const v2f alpha2 = alpha * alpha;
    const v2f dmean  = (kd0 + kd1 + kd2) * pk_bcast(1.f / 3.f);
    const v2f smean  = (ks0 + ks1 + ks2) * pk_bcast(1.f / 3.f);
    v2f pS = pk_div(smean, dmean + smean + pk_bcast(1e-6f));
    pS = pk_maxs(pS, 0.f);

    const long sbA = ((long)rayA * SPP_ + lane) * 3;
    const long sbB = ((long)rayB * SPP_ + lane) * 3;
    const v2f s0 = pk2(smp[sbA + 0], smp[sbB + 0]);
    const v2f u1 = pk2(smp[sbA + 1], smp[sbB + 1]);
    const v2f u2 = pk2(smp[sbA + 2], smp[sbB + 2]);

    const bool sdA = (s0.x >= pS.x);
    const bool sdB = (s0.y >= pS.y);

    const v2f r    = pk_sqrt(u1);
    // sin(2*pi*u2): v_sin/v_cos take revolutions, u2 in [0,1)
    const v2f sphi = pk2(__builtin_amdgcn_sinf(u2.x), __builtin_amdgcn_sinf(u2.y));
    const v2f cphi = pk2(__builtin_amdgcn_cosf(u2.x), __builtin_amdgcn_cosf(u2.y));

    const v2f ld0  = r * cphi, ld1 = r * sphi;
    const v2f omu1 = one - u1;
    const v2f ld2  = pk_sqrt(pk_maxs(omu1, 0.f));

    const v2f a2m1 = alpha2 - one;
    v2f c2 = pk_div(omu1, one + a2m1 * u1);
    c2.x = fminf(fmaxf(c2.x, 0.f), 1.f);
    c2.y = fminf(fmaxf(c2.y, 0.f), 1.f);
    const v2f ct = pk_sqrt(c2);
    const v2f st = pk_sqrt(one - c2);
    const v2f h0 = st * cphi, h1 = st * sphi, h2 = ct;

    const v2f dwh  = wi0 * h0 + wi1 * h1 + wi2 * h2;
    const v2f tdwh = dwh + dwh;
    const v2f lsp0 = tdwh * h0 - wi0;
    const v2f lsp1 = tdwh * h1 - wi1;
    const v2f lsp2 = tdwh * h2 - wi2;

    v2f wo0, wo1, wo2;
    wo0.x = sdA ? ld0.x : lsp0.x;  wo0.y = sdB ? ld0.y : lsp0.y;
    wo1.x = sdA ? ld1.x : lsp1.x;  wo1.y = sdB ? ld1.y : lsp1.y;
    wo2.x = sdA ? ld2.x : lsp2.x;  wo2.y = sdB ? ld2.y : lsp2.y;

    const v2f pdf_diff = pk_maxs(wo2, 0.f) * pk_bcast(1.f / PI_F);

    v2f hm0 = wi0 + wo0, hm1 = wi1 + wo1, hm2 = wi2 + wo2;
    {
        const v2f l2  = hm0 * hm0 + hm1 * hm1 + hm2 * hm2;
        const v2f inv = pk_rsq_clamp(l2);
        hm0 *= inv; hm1 *= inv; hm2 *= inv;
    }
    const v2f hz = hm2;
    const v2f dd = hz * hz * a2m1 + one;
    const v2f D  = pk_div(alpha2, dd * dd * pk_bcast(PI_F));

    const v2f woh = wo0 * hm0 + wo1 * hm1 + wo2 * hm2;
    const v2f pdf_spec = pk_div(D * pk_maxs(hz, 0.f),
                                pk_bcast(4.f) * pk_maxs(woh, 1e-6f));
    v2f pdfs = pS * pdf_spec + (one - pS) * pdf_diff;
    pdfs = pk_maxs(pdfs, 1e-5f);

    const v2f wiz  = pk_maxs(wi2, 1e-6f);
    const v2f woz  = pk_maxs(wo2, 1e-6f);
    const v2f oma2 = one - alpha2;
    const v2f si = pk_sqrt(alpha2 + oma2 * wiz * wiz);
    const v2f so = pk_sqrt(alpha2 + oma2 * woz * woz);
    const v2f G1i = pk_div(wiz + wiz, wiz + si);
    const v2f G1o = pk_div(woz + woz, woz + so);
    const v2f G   = G1i * G1o;

    v2f wih = wi0 * hm0 + wi1 * hm1 + wi2 * hm2;
    wih.x = fminf(fmaxf(wih.x, 0.f), 1.f);
    wih.y = fminf(fmaxf(wih.y, 0.f), 1.f);
    const v2f t1m = one - wih;
    const v2f t2s = t1m * t1m;
    const v2f f5  = t2s * t2s * t1m;
    S.fr0 = ks0 + (one - ks0) * f5;
    S.fr1 = ks1 + (one - ks1) * f5;
    S.fr2 = ks2 + (one - ks2) * f5;

    v2f ss = pk_div(D * G, pk_bcast(4.f) * wiz * woz);
    if (!(wo2.x > 0.f)) ss.x = 0.f;
    if (!(wo2.y > 0.f)) ss.y = 0.f;

    const v2f dx = wo0 * cx0 + wo1 * cy0 + wo2 * nx;
    const v2f dy = wo0 * cx1 + wo1 * cy1 + wo2 * ny;
    const v2f dz = wo0 * cx2 + wo1 * cy2 + wo2 * nz;

    const v2f p01 = pk_bcast(0.01f);
    S.f0 = spx + p01 * dx;
    S.f1 = spy + p01 * dy;
    S.f2 = spz + p01 * dz;
    S.f3 = dx; S.f4 = dy; S.f5 = dz;

    const v2f ndl = pk_maxs(wo2, 0.f);
    S.wgt = pk_div(ndl, pdfs);
    S.sw  = ss * S.wgt;
    return S;
}

__global__ __launch_bounds__(256) void render_kernel(
    const float* __restrict__ sp, const float* __restrict__ vd,
    const float* __restrict__ Kd, const float* __restrict__ Ks,
    const float* __restrict__ nrm, const float* __restrict__ rough,
    const float* __restrict__ smp,
    const float* __restrict__ W1, const float* __restrict__ b1,
    const float* __restrict__ W2, const float* __restrict__ b2,
    float* __restrict__ out)
{
    const float PI_F = 3.14159265358979323846f;

    // Pair-packed weights: row p (p=0..31) covers hidden units 2p, 2p+1.
    __shared__ __align__(16) float sPk[32][20];
    __shared__ float sb2[4];

    const int tid = threadIdx.x;
    if (tid < 32) {
        const int p = tid, j0 = 2 * tid, j1 = 2 * tid + 1;
        #pragma unroll
        for (int k = 0; k < 6; ++k) {
            sPk[p][2 * k + 0] = W1[k * 64 + j0];
            sPk[p][2 * k + 1] = W1[k * 64 + j1];
        }
        sPk[p][12] = b1[j0];
        sPk[p][13] = b1[j1];
        #pragma unroll
        for (int c = 0; c < 3; ++c) {
            sPk[p][14 + 2 * c] = W2[j0 * 3 + c];
            sPk[p][15 + 2 * c] = W2[j1 * 3 + c];
        }
    }
    if (tid < 3) sb2[tid] = b2[tid];
    __syncthreads();

    const int wave = tid >> 6;
    const int lane = tid & 63;
    const int rayA = (blockIdx.x << 3) + (wave << 1);
    const int rayB = rayA + 1;

    PairState P = shade_pair(sp, vd, Kd, Ks, nrm, rough, smp, rayA, rayB, lane);

    const v2f fA0 = pk_bcast(P.f0.x), fA1 = pk_bcast(P.f1.x), fA2 = pk_bcast(P.f2.x);
    const v2f fA3 = pk_bcast(P.f3.x), fA4 = pk_bcast(P.f4.x), fA5 = pk_bcast(P.f5.x);
    const v2f fB0 = pk_bcast(P.f0.y), fB1 = pk_bcast(P.f1.y), fB2 = pk_bcast(P.f2.y);
    const v2f fB3 = pk_bcast(P.f3.y), fB4 = pk_bcast(P.f4.y), fB5 = pk_bcast(P.f5.y);

    v2f accA0 = pk_bcast(0.f), accA1 = pk_bcast(0.f), accA2 = pk_bcast(0.f);
    v2f accB0 = pk_bcast(0.f), accB1 = pk_bcast(0.f), accB2 = pk_bcast(0.f);

    #pragma unroll 2
    for (int p = 0; p < 32; ++p) {
        const float4 q0 = *(const float4*)&sPk[p][0];
        const float4 q1 = *(const float4*)&sPk[p][4];
        const float4 q2 = *(const float4*)&sPk[p][8];
        const float4 q3 = *(const float4*)&sPk[p][12];
        const float4 q4 = *(const float4*)&sPk[p][16];
        const v2f w0 = {q0.x, q0.y}, w1 = {q0.z, q0.w};
        const v2f w2 = {q1.x, q1.y}, w3 = {q1.z, q1.w};
        const v2f w4 = {q2.x, q2.y}, w5 = {q2.z, q2.w};
        const v2f b1p = {q3.x, q3.y};
        const v2f u0 = {q3.z, q3.w}, u1 = {q4.x, q4.y}, u2 = {q4.z, q4.w};

        v2f hA = pk_fma(fA0, w0, b1p);
        hA = pk_fma(fA1, w1, hA);
        hA = pk_fma(fA2, w2, hA);
        hA = pk_fma(fA3, w3, hA);
        hA = pk_fma(fA4, w4, hA);
        hA = pk_fma(fA5, w5, hA);
        hA.x = fmaxf(hA.x, 0.f);
        hA.y = fmaxf(hA.y, 0.f);

        v2f hB = pk_fma(fB0, w0, b1p);
        hB = pk_fma(fB1, w1, hB);
        hB = pk_fma(fB2, w2, hB);
        hB = pk_fma(fB3, w3, hB);
        hB = pk_fma(fB4, w4, hB);
        hB = pk_fma(fB5, w5, hB);
        hB.x = fmaxf(hB.x, 0.f);
        hB.y = fmaxf(hB.y, 0.f);

        accA0 = pk_fma(hA, u0, accA0);
        accA1 = pk_fma(hA, u1, accA1);
        accA2 = pk_fma(hA, u2, accA2);
        accB0 = pk_fma(hB, u0, accB0);
        accB1 = pk_fma(hB, u1, accB1);
        accB2 = pk_fma(hB, u2, accB2);
    }

    float a0 = softplus_f(accA0.x + accA0.y + sb2[0]);
    float a1 = softplus_f(accA1.x + accA1.y + sb2[1]);
    float a2 = softplus_f(accA2.x + accA2.y + sb2[2]);
    float b0 = softplus_f(accB0.x + accB0.y + sb2[0]);
    float b1v = softplus_f(accB1.x + accB1.y + sb2[1]);
    float b2v = softplus_f(accB2.x + accB2.y + sb2[2]);

    float adA0 = P.wgt.x * a0, adA1 = P.wgt.x * a1, adA2 = P.wgt.x * a2;
    float asA0 = P.sw.x * P.fr0.x * a0;
    float asA1 = P.sw.x * P.fr1.x * a1;
    float asA2 = P.sw.x * P.fr2.x * a2;
    float adB0 = P.wgt.y * b0, adB1 = P.wgt.y * b1v, adB2 = P.wgt.y * b2v;
    float asB0 = P.sw.y * P.fr0.y * b0;
    float asB1 = P.sw.y * P.fr1.y * b1v;
    float asB2 = P.sw.y * P.fr2.y * b2v;

    #pragma unroll
    for (int off = 32; off > 0; off >>= 1) {
        adA0 += __shfl_down(adA0, off);
        adA1 += __shfl_down(adA1, off);
        adA2 += __shfl_down(adA2, off);
        asA0 += __shfl_down(asA0, off);
        asA1 += __shfl_down(asA1, off);
        asA2 += __shfl_down(asA2, off);
        adB0 += __shfl_down(adB0, off);
        adB1 += __shfl_down(adB1, off);
        adB2 += __shfl_down(adB2, off);
        asB0 += __shfl_down(asB0, off);
        asB1 += __shfl_down(asB1, off);
        asB2 += __shfl_down(asB2, off);
    }

    if (lane == 0) {
        const float cdi = 1.f / (PI_F * (float)SPP_);
        const float csi = 1.f / (float)SPP_;
        out[rayA * 3 + 0] = Kd[rayA * 3 + 0] * cdi * adA0;
        out[rayA * 3 + 1] = Kd[rayA * 3 + 1] * cdi * adA1;
        out[rayA * 3 + 2] = Kd[rayA * 3 + 2] * cdi * adA2;
        out[BN_ * 3 + rayA * 3 + 0] = asA0 * csi;
        out[BN_ * 3 + rayA * 3 + 1] = asA1 * csi;
        out[BN_ * 3 + rayA * 3 + 2] = asA2 * csi;
        out[BN_ * 6 + rayA] = P.wimA;

        out[rayB * 3 + 0] = Kd[rayB * 3 + 0] * cdi * adB0;
        out[rayB * 3 + 1] = Kd[rayB * 3 + 1] * cdi * adB1;
        out[rayB * 3 + 2] = Kd[rayB * 3 + 2] * cdi * adB2;
        out[BN_ * 3 + rayB * 3 + 0] = asB0 * csi;
        out[BN_ * 3 + rayB * 3 + 1] = asB1 * csi;
        out[BN_ * 3 + rayB * 3 + 2] = asB2 * csi;
        out[BN_ * 6 + rayB] = P.wimB;
    }
}

extern "C" void kernel_launch(void* const* d_in, const int* in_sizes, int n_in,
                              void* d_out, int out_size, void* d_ws, size_t ws_size,
                              hipStream_t stream) {
    const float* sp    = (const float*)d_in[0];
    const float* vd    = (const float*)d_in[1];
    const float* Kd    = (const float*)d_in[2];
    const float* Ks    = (const float*)d_in[3];
    const float* nrm   = (const float*)d_in[4];
    const float* rough = (const float*)d_in[5];
    const float* smp   = (const float*)d_in[6];
    const float* W1    = (const float*)d_in[7];
    const float* b1    = (const float*)d_in[8];
    const float* W2    = (const float*)d_in[9];
    const float* b2    = (const float*)d_in[10];
    float* out = (float*)d_out;

    dim3 grid(BN_ / 8);
    dim3 block(256);
    render_kernel<<<grid, block, 0, stream>>>(sp, vd, Kd, Ks, nrm, rough, smp,
                                              W1, b1, W2, b2, out);
}